// Round 1
// baseline (5844.971 us; speedup 1.0000x reference)
//
#include <hip/hip_runtime.h>
#include <hip/hip_bf16.h>
#include <stdint.h>

#define N_NODES 100000
#define DIM 256
#define HID 512
#define N_EDGES 1600000

using short8 = __attribute__((ext_vector_type(8))) short;
using f32x4  = __attribute__((ext_vector_type(4))) float;

__device__ __forceinline__ unsigned short f2bf(float f) {
    union { float f; unsigned u; } v; v.f = f;
    unsigned u = v.u;
    unsigned r = u + 0x7fffu + ((u >> 16) & 1u);   // RNE
    return (unsigned short)(r >> 16);
}

// acc = (1 + eps) * x   (float4 per thread, exact grid)
__global__ void init_acc(const float* __restrict__ x, const float* __restrict__ eps,
                         float* __restrict__ acc) {
    long i = (long)blockIdx.x * blockDim.x + threadIdx.x;
    float s = 1.0f + eps[0];
    float4 v = ((const float4*)x)[i];
    float4 o; o.x = v.x * s; o.y = v.y * s; o.z = v.z * s; o.w = v.w * s;
    ((float4*)acc)[i] = o;
}

// one wave per edge: 64 lanes x float4 = full 256-float row
__global__ void scatter_add(const float* __restrict__ x, const int* __restrict__ src,
                            const int* __restrict__ dst, float* __restrict__ acc) {
    int lane = threadIdx.x & 63;
    int e = blockIdx.x * 4 + (threadIdx.x >> 6);
    if (e >= N_EDGES) return;
    int s = src[e];
    int d = dst[e];
    float4 v = ((const float4*)(x + (size_t)s * DIM))[lane];
    float* a = acc + (size_t)d * DIM + lane * 4;
    unsafeAtomicAdd(a + 0, v.x);
    unsafeAtomicAdd(a + 1, v.y);
    unsafeAtomicAdd(a + 2, v.z);
    unsafeAtomicAdd(a + 3, v.w);
}

// W1 [256,512] -> W1t bf16 [512][256] (n-major); W2 [512,256] -> W2t bf16 [256][512]
__global__ void prep_weights(const float* __restrict__ W1, const float* __restrict__ W2,
                             unsigned short* __restrict__ W1t, unsigned short* __restrict__ W2t) {
    int tid = blockIdx.x * blockDim.x + threadIdx.x;
    if (tid < DIM * HID) {
        int n = tid >> 8, k = tid & 255;          // n<512, k<256
        W1t[tid] = f2bf(W1[k * HID + n]);
    } else {
        int j = tid - DIM * HID;
        int n = j >> 9, k = j & 511;              // n<256, k<512
        W2t[j] = f2bf(W2[k * DIM + n]);
    }
}

// 64x64 block tile, 4 waves in 2x2, each wave 32x32 via 2x2 of 16x16x32 MFMA.
// A: row-major [M,K] (fp32 or bf16). Bt: n-major bf16 [NOUT][K].
template<int K, int NOUT, bool A_F32, bool RELU_BF16_OUT>
__global__ __launch_bounds__(256) void gemm_mfma(const void* __restrict__ Ain,
        const unsigned short* __restrict__ Bt, const float* __restrict__ bias,
        void* __restrict__ Cout, int M) {
    __shared__ unsigned short As[64 * 40];   // row stride 40 bf16 = 80 B (16B aligned)
    __shared__ unsigned short Bs[64 * 40];
    constexpr int NT = NOUT / 64;
    int mtile = blockIdx.x / NT;
    int ntile = blockIdx.x % NT;
    int mbase = mtile * 64, nbase = ntile * 64;
    int t = threadIdx.x;
    int lane = t & 63, wid = t >> 6;
    int wm = (wid & 1) * 32, wn = (wid >> 1) * 32;
    int lo = lane & 15, quad = lane >> 4, ko = quad * 8;
    int sm = t >> 2, skc = (t & 3) * 8;      // staging: row sm, k-chunk of 8

    f32x4 acc[2][2] = {};
    for (int kt = 0; kt < K / 32; ++kt) {
        if (kt) __syncthreads();
        // ---- stage A tile (64 x 32) ----
        int gm = mbase + sm;
        short8 av;
        if (gm < M) {
            if constexpr (A_F32) {
                const float* ap = (const float*)Ain + (size_t)gm * K + kt * 32 + skc;
                float4 u0 = *(const float4*)ap;
                float4 u1 = *(const float4*)(ap + 4);
                av[0] = (short)f2bf(u0.x); av[1] = (short)f2bf(u0.y);
                av[2] = (short)f2bf(u0.z); av[3] = (short)f2bf(u0.w);
                av[4] = (short)f2bf(u1.x); av[5] = (short)f2bf(u1.y);
                av[6] = (short)f2bf(u1.z); av[7] = (short)f2bf(u1.w);
            } else {
                av = *(const short8*)((const unsigned short*)Ain + (size_t)gm * K + kt * 32 + skc);
            }
        } else {
            av = (short8){0, 0, 0, 0, 0, 0, 0, 0};
        }
        *(short8*)&As[sm * 40 + skc] = av;
        // ---- stage B tile (64 n-rows x 32 k) ----
        short8 bv = *(const short8*)(Bt + (size_t)(nbase + sm) * K + kt * 32 + skc);
        *(short8*)&Bs[sm * 40 + skc] = bv;
        __syncthreads();
        // ---- fragments + MFMA ----
        short8 a0 = *(const short8*)&As[(wm + lo) * 40 + ko];
        short8 a1 = *(const short8*)&As[(wm + 16 + lo) * 40 + ko];
        short8 b0 = *(const short8*)&Bs[(wn + lo) * 40 + ko];
        short8 b1 = *(const short8*)&Bs[(wn + 16 + lo) * 40 + ko];
        acc[0][0] = __builtin_amdgcn_mfma_f32_16x16x32_bf16(a0, b0, acc[0][0], 0, 0, 0);
        acc[1][0] = __builtin_amdgcn_mfma_f32_16x16x32_bf16(a1, b0, acc[1][0], 0, 0, 0);
        acc[0][1] = __builtin_amdgcn_mfma_f32_16x16x32_bf16(a0, b1, acc[0][1], 0, 0, 0);
        acc[1][1] = __builtin_amdgcn_mfma_f32_16x16x32_bf16(a1, b1, acc[1][1], 0, 0, 0);
    }
    // ---- epilogue: D layout col=lane&15, row=quad*4+reg ----
    #pragma unroll
    for (int mi = 0; mi < 2; ++mi)
      #pragma unroll
      for (int ni = 0; ni < 2; ++ni)
        #pragma unroll
        for (int r = 0; r < 4; ++r) {
            int row = mbase + wm + mi * 16 + quad * 4 + r;
            int col = nbase + wn + ni * 16 + lo;
            if (row < M) {
                float v = acc[mi][ni][r] + bias[col];
                if constexpr (RELU_BF16_OUT) {
                    v = fmaxf(v, 0.0f);
                    ((unsigned short*)Cout)[(size_t)row * NOUT + col] = f2bf(v);
                } else {
                    ((float*)Cout)[(size_t)row * NOUT + col] = v;
                }
            }
        }
}

// per-column partial sums over a row stripe: one column per thread, coalesced rows
__global__ void col_stats1(const float* __restrict__ h, float* __restrict__ partial) {
    int t = threadIdx.x;
    int b = blockIdx.x;
    int r0 = b * 391;
    int r1 = r0 + 391; if (r1 > N_NODES) r1 = N_NODES;
    float s = 0.f, q = 0.f;
    for (int r = r0; r < r1; ++r) {
        float v = h[(size_t)r * DIM + t];
        s += v; q += v * v;
    }
    partial[b * 512 + t] = s;
    partial[b * 512 + 256 + t] = q;
}

// combine 256 partials -> scale/shift per column
__global__ void col_stats2(const float* __restrict__ partial, const float* __restrict__ gamma,
                           const float* __restrict__ beta, float* __restrict__ sc) {
    int t = threadIdx.x;
    float s = 0.f, q = 0.f;
    for (int b = 0; b < 256; ++b) {
        s += partial[b * 512 + t];
        q += partial[b * 512 + 256 + t];
    }
    float mean = s * (1.0f / (float)N_NODES);
    float var = q * (1.0f / (float)N_NODES) - mean * mean;
    float inv = rsqrtf(var + 1e-5f);
    float scale = gamma[t] * inv;
    sc[t] = scale;
    sc[256 + t] = beta[t] - mean * scale;
}

__global__ void bn_apply(const float* __restrict__ h, const float* __restrict__ sc,
                         float* __restrict__ out) {
    long i = (long)blockIdx.x * blockDim.x + threadIdx.x;   // float4 index
    int c = (int)((i * 4) & (DIM - 1));
    float4 v = ((const float4*)h)[i];
    float4 scale = *(const float4*)(sc + c);
    float4 shift = *(const float4*)(sc + 256 + c);
    float4 o;
    o.x = v.x * scale.x + shift.x;
    o.y = v.y * scale.y + shift.y;
    o.z = v.z * scale.z + shift.z;
    o.w = v.w * scale.w + shift.w;
    ((float4*)out)[i] = o;
}

extern "C" void kernel_launch(void* const* d_in, const int* in_sizes, int n_in,
                              void* d_out, int out_size, void* d_ws, size_t ws_size,
                              hipStream_t stream) {
    const float* x     = (const float*)d_in[0];
    const int*   src   = (const int*)d_in[1];
    const int*   dst   = (const int*)d_in[2];
    const float* eps   = (const float*)d_in[3];
    const float* W1    = (const float*)d_in[4];
    const float* b1    = (const float*)d_in[5];
    const float* W2    = (const float*)d_in[6];
    const float* b2    = (const float*)d_in[7];
    const float* gamma = (const float*)d_in[8];
    const float* beta  = (const float*)d_in[9];

    char* ws = (char*)d_ws;
    float*          acc     = (float*)ws;                         // 102,400,000 B (h1, then h2)
    unsigned short* W1t     = (unsigned short*)(ws + 102400000);  // 262,144 B
    unsigned short* W2t     = (unsigned short*)(ws + 102662144);  // 262,144 B
    float*          partial = (float*)(ws + 102924288);           // 524,288 B
    float*          sc      = (float*)(ws + 103448576);           // 2,048 B
    unsigned short* tbuf    = (unsigned short*)d_out;             // N x 512 bf16 == d_out bytes
    float*          out     = (float*)d_out;

    hipLaunchKernelGGL(prep_weights, dim3(1024), dim3(256), 0, stream, W1, W2, W1t, W2t);
    hipLaunchKernelGGL(init_acc, dim3(25000), dim3(256), 0, stream, x, eps, acc);
    hipLaunchKernelGGL(scatter_add, dim3(N_EDGES / 4), dim3(256), 0, stream, x, src, dst, acc);
    hipLaunchKernelGGL((gemm_mfma<256, 512, true, true>), dim3(1563 * 8), dim3(256), 0, stream,
                       (const void*)acc, W1t, b1, (void*)tbuf, N_NODES);
    hipLaunchKernelGGL((gemm_mfma<512, 256, false, false>), dim3(1563 * 4), dim3(256), 0, stream,
                       (const void*)tbuf, W2t, b2, (void*)acc, N_NODES);
    hipLaunchKernelGGL(col_stats1, dim3(256), dim3(256), 0, stream, acc, partial);
    hipLaunchKernelGGL(col_stats2, dim3(1), dim3(256), 0, stream, partial, gamma, beta, sc);
    hipLaunchKernelGGL(bn_apply, dim3(25000), dim3(256), 0, stream, acc, sc, out);
}

// Round 2
// 943.718 us; speedup vs baseline: 6.1936x; 6.1936x over previous
//
#include <hip/hip_runtime.h>
#include <hip/hip_bf16.h>
#include <stdint.h>

#define N_NODES 100000
#define DIM 256
#define HID 512
#define N_EDGES 1600000
#define NCHUNK 391                 // 391*256 = 100096 >= N_NODES
#define NPAD (NCHUNK * 256)

using short8 = __attribute__((ext_vector_type(8))) short;
using f32x4  = __attribute__((ext_vector_type(4))) float;

__device__ __forceinline__ unsigned short f2bf(float f) {
    union { float f; unsigned u; } v; v.f = f;
    unsigned u = v.u;
    unsigned r = u + 0x7fffu + ((u >> 16) & 1u);   // RNE
    return (unsigned short)(r >> 16);
}

// ---------------- counting-sort (CSR by dst) ----------------

__global__ void zero_counts(int* __restrict__ count) {
    count[blockIdx.x * 256 + threadIdx.x] = 0;
}

__global__ void histogram(const int* __restrict__ dst, int* __restrict__ count) {
    int e = blockIdx.x * 256 + threadIdx.x;
    atomicAdd(&count[dst[e]], 1);
}

__global__ void chunk_sums(const int* __restrict__ count, int* __restrict__ chunkSums) {
    __shared__ int sm[256];
    int t = threadIdx.x;
    sm[t] = count[blockIdx.x * 256 + t];
    __syncthreads();
    for (int s = 128; s > 0; s >>= 1) {
        if (t < s) sm[t] += sm[t + s];
        __syncthreads();
    }
    if (t == 0) chunkSums[blockIdx.x] = sm[0];
}

// 1 block x 512 threads: exclusive scan of 391 chunk sums (padded to 512)
__global__ void scan_chunks(const int* __restrict__ chunkSums, int* __restrict__ chunkOff) {
    __shared__ int sm[512];
    int t = threadIdx.x;
    int v = (t < NCHUNK) ? chunkSums[t] : 0;
    sm[t] = v;
    __syncthreads();
    for (int off = 1; off < 512; off <<= 1) {
        int add = (t >= off) ? sm[t - off] : 0;
        __syncthreads();
        sm[t] += add;
        __syncthreads();
    }
    chunkOff[t] = sm[t] - v;   // exclusive
}

// per-chunk exclusive scan + chunk offset -> start[], cursor[]
__global__ void scan_within(const int* __restrict__ count, const int* __restrict__ chunkOff,
                            int* __restrict__ start, int* __restrict__ cursor) {
    __shared__ int sm[256];
    int t = threadIdx.x;
    int gid = blockIdx.x * 256 + t;
    int v = count[gid];
    sm[t] = v;
    __syncthreads();
    for (int off = 1; off < 256; off <<= 1) {
        int add = (t >= off) ? sm[t - off] : 0;
        __syncthreads();
        sm[t] += add;
        __syncthreads();
    }
    int sv = sm[t] - v + chunkOff[blockIdx.x];
    start[gid] = sv;
    cursor[gid] = sv;
}

__global__ void scatter_pos(const int* __restrict__ src, const int* __restrict__ dst,
                            int* __restrict__ cursor, int* __restrict__ sorted_src) {
    int e = blockIdx.x * 256 + threadIdx.x;
    int pos = atomicAdd(&cursor[dst[e]], 1);
    sorted_src[pos] = src[e];
}

// one wave per node: acc[n] = (1+eps)*x[n] + sum over CSR neighbors
__global__ void gather_sum(const float* __restrict__ x, const int* __restrict__ sorted_src,
                           const int* __restrict__ start, const int* __restrict__ count,
                           const float* __restrict__ eps, float* __restrict__ acc) {
    int lane = threadIdx.x & 63;
    int n = blockIdx.x * 4 + (threadIdx.x >> 6);
    if (n >= N_NODES) return;
    float s = 1.0f + eps[0];
    float4 v = ((const float4*)(x + (size_t)n * DIM))[lane];
    float ax = v.x * s, ay = v.y * s, az = v.z * s, aw = v.w * s;
    int base = start[n];
    int end = base + count[n];
    int j = base;
    for (; j + 2 <= end; j += 2) {
        int s0 = sorted_src[j];
        int s1 = sorted_src[j + 1];
        float4 v0 = ((const float4*)(x + (size_t)s0 * DIM))[lane];
        float4 v1 = ((const float4*)(x + (size_t)s1 * DIM))[lane];
        ax += v0.x + v1.x; ay += v0.y + v1.y;
        az += v0.z + v1.z; aw += v0.w + v1.w;
    }
    if (j < end) {
        int s0 = sorted_src[j];
        float4 v0 = ((const float4*)(x + (size_t)s0 * DIM))[lane];
        ax += v0.x; ay += v0.y; az += v0.z; aw += v0.w;
    }
    float4 o; o.x = ax; o.y = ay; o.z = az; o.w = aw;
    ((float4*)(acc + (size_t)n * DIM))[lane] = o;
}

// ---------------- MLP + BN (unchanged from round 1) ----------------

__global__ void prep_weights(const float* __restrict__ W1, const float* __restrict__ W2,
                             unsigned short* __restrict__ W1t, unsigned short* __restrict__ W2t) {
    int tid = blockIdx.x * blockDim.x + threadIdx.x;
    if (tid < DIM * HID) {
        int n = tid >> 8, k = tid & 255;
        W1t[tid] = f2bf(W1[k * HID + n]);
    } else {
        int j = tid - DIM * HID;
        int n = j >> 9, k = j & 511;
        W2t[j] = f2bf(W2[k * DIM + n]);
    }
}

template<int K, int NOUT, bool A_F32, bool RELU_BF16_OUT>
__global__ __launch_bounds__(256) void gemm_mfma(const void* __restrict__ Ain,
        const unsigned short* __restrict__ Bt, const float* __restrict__ bias,
        void* __restrict__ Cout, int M) {
    __shared__ unsigned short As[64 * 40];
    __shared__ unsigned short Bs[64 * 40];
    constexpr int NT = NOUT / 64;
    int mtile = blockIdx.x / NT;
    int ntile = blockIdx.x % NT;
    int mbase = mtile * 64, nbase = ntile * 64;
    int t = threadIdx.x;
    int lane = t & 63, wid = t >> 6;
    int wm = (wid & 1) * 32, wn = (wid >> 1) * 32;
    int lo = lane & 15, quad = lane >> 4, ko = quad * 8;
    int sm = t >> 2, skc = (t & 3) * 8;

    f32x4 acc[2][2] = {};
    for (int kt = 0; kt < K / 32; ++kt) {
        if (kt) __syncthreads();
        int gm = mbase + sm;
        short8 av;
        if (gm < M) {
            if constexpr (A_F32) {
                const float* ap = (const float*)Ain + (size_t)gm * K + kt * 32 + skc;
                float4 u0 = *(const float4*)ap;
                float4 u1 = *(const float4*)(ap + 4);
                av[0] = (short)f2bf(u0.x); av[1] = (short)f2bf(u0.y);
                av[2] = (short)f2bf(u0.z); av[3] = (short)f2bf(u0.w);
                av[4] = (short)f2bf(u1.x); av[5] = (short)f2bf(u1.y);
                av[6] = (short)f2bf(u1.z); av[7] = (short)f2bf(u1.w);
            } else {
                av = *(const short8*)((const unsigned short*)Ain + (size_t)gm * K + kt * 32 + skc);
            }
        } else {
            av = (short8){0, 0, 0, 0, 0, 0, 0, 0};
        }
        *(short8*)&As[sm * 40 + skc] = av;
        short8 bv = *(const short8*)(Bt + (size_t)(nbase + sm) * K + kt * 32 + skc);
        *(short8*)&Bs[sm * 40 + skc] = bv;
        __syncthreads();
        short8 a0 = *(const short8*)&As[(wm + lo) * 40 + ko];
        short8 a1 = *(const short8*)&As[(wm + 16 + lo) * 40 + ko];
        short8 b0 = *(const short8*)&Bs[(wn + lo) * 40 + ko];
        short8 b1 = *(const short8*)&Bs[(wn + 16 + lo) * 40 + ko];
        acc[0][0] = __builtin_amdgcn_mfma_f32_16x16x32_bf16(a0, b0, acc[0][0], 0, 0, 0);
        acc[1][0] = __builtin_amdgcn_mfma_f32_16x16x32_bf16(a1, b0, acc[1][0], 0, 0, 0);
        acc[0][1] = __builtin_amdgcn_mfma_f32_16x16x32_bf16(a0, b1, acc[0][1], 0, 0, 0);
        acc[1][1] = __builtin_amdgcn_mfma_f32_16x16x32_bf16(a1, b1, acc[1][1], 0, 0, 0);
    }
    #pragma unroll
    for (int mi = 0; mi < 2; ++mi)
      #pragma unroll
      for (int ni = 0; ni < 2; ++ni)
        #pragma unroll
        for (int r = 0; r < 4; ++r) {
            int row = mbase + wm + mi * 16 + quad * 4 + r;
            int col = nbase + wn + ni * 16 + lo;
            if (row < M) {
                float v = acc[mi][ni][r] + bias[col];
                if constexpr (RELU_BF16_OUT) {
                    v = fmaxf(v, 0.0f);
                    ((unsigned short*)Cout)[(size_t)row * NOUT + col] = f2bf(v);
                } else {
                    ((float*)Cout)[(size_t)row * NOUT + col] = v;
                }
            }
        }
}

__global__ void col_stats1(const float* __restrict__ h, float* __restrict__ partial) {
    int t = threadIdx.x;
    int b = blockIdx.x;
    int r0 = b * 391;
    int r1 = r0 + 391; if (r1 > N_NODES) r1 = N_NODES;
    float s = 0.f, q = 0.f;
    for (int r = r0; r < r1; ++r) {
        float v = h[(size_t)r * DIM + t];
        s += v; q += v * v;
    }
    partial[b * 512 + t] = s;
    partial[b * 512 + 256 + t] = q;
}

__global__ void col_stats2(const float* __restrict__ partial, const float* __restrict__ gamma,
                           const float* __restrict__ beta, float* __restrict__ sc) {
    int t = threadIdx.x;
    float s = 0.f, q = 0.f;
    for (int b = 0; b < 256; ++b) {
        s += partial[b * 512 + t];
        q += partial[b * 512 + 256 + t];
    }
    float mean = s * (1.0f / (float)N_NODES);
    float var = q * (1.0f / (float)N_NODES) - mean * mean;
    float inv = rsqrtf(var + 1e-5f);
    float scale = gamma[t] * inv;
    sc[t] = scale;
    sc[256 + t] = beta[t] - mean * scale;
}

__global__ void bn_apply(const float* __restrict__ h, const float* __restrict__ sc,
                         float* __restrict__ out) {
    long i = (long)blockIdx.x * blockDim.x + threadIdx.x;
    int c = (int)((i * 4) & (DIM - 1));
    float4 v = ((const float4*)h)[i];
    float4 scale = *(const float4*)(sc + c);
    float4 shift = *(const float4*)(sc + 256 + c);
    float4 o;
    o.x = v.x * scale.x + shift.x;
    o.y = v.y * scale.y + shift.y;
    o.z = v.z * scale.z + shift.z;
    o.w = v.w * scale.w + shift.w;
    ((float4*)out)[i] = o;
}

extern "C" void kernel_launch(void* const* d_in, const int* in_sizes, int n_in,
                              void* d_out, int out_size, void* d_ws, size_t ws_size,
                              hipStream_t stream) {
    const float* x     = (const float*)d_in[0];
    const int*   src   = (const int*)d_in[1];
    const int*   dst   = (const int*)d_in[2];
    const float* eps   = (const float*)d_in[3];
    const float* W1    = (const float*)d_in[4];
    const float* b1    = (const float*)d_in[5];
    const float* W2    = (const float*)d_in[6];
    const float* b2    = (const float*)d_in[7];
    const float* gamma = (const float*)d_in[8];
    const float* beta  = (const float*)d_in[9];

    char* ws = (char*)d_ws;
    float*          acc     = (float*)ws;                         // 102,400,000 B
    unsigned short* W1t     = (unsigned short*)(ws + 102400000);  // 262,144 B
    unsigned short* W2t     = (unsigned short*)(ws + 102662144);  // 262,144 B
    float*          partial = (float*)(ws + 102924288);           // 524,288 B  (post-GEMM only)
    float*          sc      = (float*)(ws + 103448576);           // 2,048 B

    // sort scratch lives in d_out (dead before GEMM1 reuses d_out as tbuf)
    char* ob = (char*)d_out;
    int* count      = (int*)ob;                    // 400,384 B (NPAD ints)
    int* start      = (int*)(ob + 400384);         // 400,384 B
    int* cursor     = (int*)(ob + 800768);         // 400,384 B
    int* chunkSums  = (int*)(ob + 1201152);        // 2,048 B
    int* chunkOff   = (int*)(ob + 1203200);        // 2,048 B
    int* sorted_src = (int*)(ob + 1205248);        // 6,400,000 B

    unsigned short* tbuf = (unsigned short*)d_out; // N x 512 bf16 == d_out bytes
    float*          out  = (float*)d_out;

    hipLaunchKernelGGL(prep_weights, dim3(1024), dim3(256), 0, stream, W1, W2, W1t, W2t);
    hipLaunchKernelGGL(zero_counts, dim3(NCHUNK), dim3(256), 0, stream, count);
    hipLaunchKernelGGL(histogram, dim3(N_EDGES / 256), dim3(256), 0, stream, dst, count);
    hipLaunchKernelGGL(chunk_sums, dim3(NCHUNK), dim3(256), 0, stream, count, chunkSums);
    hipLaunchKernelGGL(scan_chunks, dim3(1), dim3(512), 0, stream, chunkSums, chunkOff);
    hipLaunchKernelGGL(scan_within, dim3(NCHUNK), dim3(256), 0, stream, count, chunkOff, start, cursor);
    hipLaunchKernelGGL(scatter_pos, dim3(N_EDGES / 256), dim3(256), 0, stream, src, dst, cursor, sorted_src);
    hipLaunchKernelGGL(gather_sum, dim3((N_NODES + 3) / 4), dim3(256), 0, stream,
                       x, sorted_src, start, count, eps, acc);
    hipLaunchKernelGGL((gemm_mfma<256, 512, true, true>), dim3(1563 * 8), dim3(256), 0, stream,
                       (const void*)acc, W1t, b1, (void*)tbuf, N_NODES);
    hipLaunchKernelGGL((gemm_mfma<512, 256, false, false>), dim3(1563 * 4), dim3(256), 0, stream,
                       (const void*)tbuf, W2t, b2, (void*)acc, N_NODES);
    hipLaunchKernelGGL(col_stats1, dim3(256), dim3(256), 0, stream, acc, partial);
    hipLaunchKernelGGL(col_stats2, dim3(1), dim3(256), 0, stream, partial, gamma, beta, sc);
    hipLaunchKernelGGL(bn_apply, dim3(25000), dim3(256), 0, stream, acc, sc, out);
}

// Round 3
// 746.821 us; speedup vs baseline: 7.8265x; 1.2636x over previous
//
#include <hip/hip_runtime.h>
#include <hip/hip_bf16.h>
#include <stdint.h>

#define N_NODES 100000
#define DIM 256
#define HID 512
#define N_EDGES 1600000
#define NCHUNK 391                 // 391*256 = 100096 >= N_NODES

using short8 = __attribute__((ext_vector_type(8))) short;
using f32x4  = __attribute__((ext_vector_type(4))) float;

__device__ __forceinline__ unsigned short f2bf(float f) {
    union { float f; unsigned u; } v; v.f = f;
    unsigned u = v.u;
    unsigned r = u + 0x7fffu + ((u >> 16) & 1u);   // RNE
    return (unsigned short)(r >> 16);
}
__device__ __forceinline__ float bf2f(unsigned short u) {
    union { unsigned u; float f; } v; v.u = ((unsigned)u) << 16; return v.f;
}
__device__ __forceinline__ void gload_lds16(const void* g, void* l) {
    __builtin_amdgcn_global_load_lds((const __attribute__((address_space(1))) void*)g,
                                     (__attribute__((address_space(3))) void*)l, 16, 0, 0);
}

// x fp32 -> bf16, 8 elems/thread
__global__ void x2bf(const float* __restrict__ x, unsigned short* __restrict__ xb) {
    long i = (long)blockIdx.x * blockDim.x + threadIdx.x;
    float4 u0 = ((const float4*)x)[i * 2];
    float4 u1 = ((const float4*)x)[i * 2 + 1];
    short8 o;
    o[0] = (short)f2bf(u0.x); o[1] = (short)f2bf(u0.y);
    o[2] = (short)f2bf(u0.z); o[3] = (short)f2bf(u0.w);
    o[4] = (short)f2bf(u1.x); o[5] = (short)f2bf(u1.y);
    o[6] = (short)f2bf(u1.z); o[7] = (short)f2bf(u1.w);
    ((short8*)xb)[i] = o;
}

// ---------------- counting-sort (CSR by dst) ----------------

__global__ void zero_counts(int* __restrict__ count) {
    count[blockIdx.x * 256 + threadIdx.x] = 0;
}

__global__ void histogram(const int* __restrict__ dst, int* __restrict__ count) {
    int e = blockIdx.x * 256 + threadIdx.x;
    atomicAdd(&count[dst[e]], 1);
}

__global__ void chunk_sums(const int* __restrict__ count, int* __restrict__ chunkSums) {
    __shared__ int sm[256];
    int t = threadIdx.x;
    sm[t] = count[blockIdx.x * 256 + t];
    __syncthreads();
    for (int s = 128; s > 0; s >>= 1) {
        if (t < s) sm[t] += sm[t + s];
        __syncthreads();
    }
    if (t == 0) chunkSums[blockIdx.x] = sm[0];
}

__global__ void scan_chunks(const int* __restrict__ chunkSums, int* __restrict__ chunkOff) {
    __shared__ int sm[512];
    int t = threadIdx.x;
    int v = (t < NCHUNK) ? chunkSums[t] : 0;
    sm[t] = v;
    __syncthreads();
    for (int off = 1; off < 512; off <<= 1) {
        int add = (t >= off) ? sm[t - off] : 0;
        __syncthreads();
        sm[t] += add;
        __syncthreads();
    }
    chunkOff[t] = sm[t] - v;   // exclusive
}

__global__ void scan_within(const int* __restrict__ count, const int* __restrict__ chunkOff,
                            int* __restrict__ start, int* __restrict__ cursor) {
    __shared__ int sm[256];
    int t = threadIdx.x;
    int gid = blockIdx.x * 256 + t;
    int v = count[gid];
    sm[t] = v;
    __syncthreads();
    for (int off = 1; off < 256; off <<= 1) {
        int add = (t >= off) ? sm[t - off] : 0;
        __syncthreads();
        sm[t] += add;
        __syncthreads();
    }
    int sv = sm[t] - v + chunkOff[blockIdx.x];
    start[gid] = sv;
    cursor[gid] = sv;
}

__global__ void scatter_pos(const int* __restrict__ src, const int* __restrict__ dst,
                            int* __restrict__ cursor, int* __restrict__ sorted_src) {
    int e = blockIdx.x * 256 + threadIdx.x;
    int pos = atomicAdd(&cursor[dst[e]], 1);
    sorted_src[pos] = src[e];
}

// one wave per node, bf16 rows: accb[n] = bf16( (1+eps)*x[n] + sum_neigh x[s] )
__global__ void gather_sum(const unsigned short* __restrict__ xb, const int* __restrict__ sorted_src,
                           const int* __restrict__ start, const int* __restrict__ count,
                           const float* __restrict__ eps, unsigned short* __restrict__ accb) {
    int lane = threadIdx.x & 63;
    int n = blockIdx.x * 4 + (threadIdx.x >> 6);
    if (n >= N_NODES) return;
    float s = 1.0f + eps[0];
    const ushort4* xr = (const ushort4*)(xb + (size_t)n * DIM);
    ushort4 v = xr[lane];
    float a0 = bf2f(v.x) * s, a1 = bf2f(v.y) * s, a2 = bf2f(v.z) * s, a3 = bf2f(v.w) * s;
    int base = start[n];
    int end = base + count[n];
    int j = base;
    for (; j + 4 <= end; j += 4) {
        int s0 = sorted_src[j], s1 = sorted_src[j + 1];
        int s2 = sorted_src[j + 2], s3 = sorted_src[j + 3];
        ushort4 v0 = ((const ushort4*)(xb + (size_t)s0 * DIM))[lane];
        ushort4 v1 = ((const ushort4*)(xb + (size_t)s1 * DIM))[lane];
        ushort4 v2 = ((const ushort4*)(xb + (size_t)s2 * DIM))[lane];
        ushort4 v3 = ((const ushort4*)(xb + (size_t)s3 * DIM))[lane];
        a0 += bf2f(v0.x) + bf2f(v1.x) + bf2f(v2.x) + bf2f(v3.x);
        a1 += bf2f(v0.y) + bf2f(v1.y) + bf2f(v2.y) + bf2f(v3.y);
        a2 += bf2f(v0.z) + bf2f(v1.z) + bf2f(v2.z) + bf2f(v3.z);
        a3 += bf2f(v0.w) + bf2f(v1.w) + bf2f(v2.w) + bf2f(v3.w);
    }
    for (; j < end; ++j) {
        int s0 = sorted_src[j];
        ushort4 v0 = ((const ushort4*)(xb + (size_t)s0 * DIM))[lane];
        a0 += bf2f(v0.x); a1 += bf2f(v0.y); a2 += bf2f(v0.z); a3 += bf2f(v0.w);
    }
    ushort4 o;
    o.x = f2bf(a0); o.y = f2bf(a1); o.z = f2bf(a2); o.w = f2bf(a3);
    ((ushort4*)(accb + (size_t)n * DIM))[lane] = o;
}

// ---------------- MLP ----------------

__global__ void prep_weights(const float* __restrict__ W1, const float* __restrict__ W2,
                             unsigned short* __restrict__ W1t, unsigned short* __restrict__ W2t) {
    int tid = blockIdx.x * blockDim.x + threadIdx.x;
    if (tid < DIM * HID) {
        int n = tid >> 8, k = tid & 255;
        W1t[tid] = f2bf(W1[k * HID + n]);
    } else {
        int j = tid - DIM * HID;
        int n = j >> 9, k = j & 511;
        W2t[j] = f2bf(W2[k * DIM + n]);
    }
}

// 128x128 tile, 4 waves (2x2), each 64x64 via 4x4 of 16x16x32 bf16 MFMA.
// global_load_lds(16B) staging; LDS chunk XOR-swizzle keeps ds_read_b128 at 2-way.
// A row-major bf16 [M][K]; Bt n-major bf16 [NOUT][K].
template<int K, int NOUT, bool RELU_BF16_OUT>
__global__ __launch_bounds__(256) void gemm128(const unsigned short* __restrict__ A,
        const unsigned short* __restrict__ Bt, const float* __restrict__ bias,
        void* __restrict__ Cout, int M) {
    __shared__ unsigned short As[128 * 32];   // 8 KB, row stride 64 B, no pad
    __shared__ unsigned short Bs[128 * 32];
    constexpr int NT = NOUT / 128;
    int mtile = blockIdx.x / NT;
    int ntile = blockIdx.x % NT;
    int mbase = mtile * 128, nbase = ntile * 128;
    int t = threadIdx.x;
    int lane = t & 63, wid = t >> 6;
    int wm = (wid & 1) * 64, wn = (wid >> 1) * 64;
    int lo = lane & 15, quad = lane >> 4;

    // staging slot -> (row, stored-chunk, global-chunk)
    int s0 = t, s1 = t + 256;
    int r0 = s0 >> 2, c0 = (s0 & 3) ^ ((r0 >> 1) & 3);
    int r1 = s1 >> 2, c1 = (s1 & 3) ^ ((r1 >> 1) & 3);
    int gmA0 = mbase + r0; if (gmA0 >= M) gmA0 = M - 1;
    int gmA1 = mbase + r1; if (gmA1 >= M) gmA1 = M - 1;
    const unsigned short* gA0 = A + (size_t)gmA0 * K + c0 * 8;
    const unsigned short* gA1 = A + (size_t)gmA1 * K + c1 * 8;
    const unsigned short* gB0 = Bt + (size_t)(nbase + r0) * K + c0 * 8;
    const unsigned short* gB1 = Bt + (size_t)(nbase + r1) * K + c1 * 8;
    char* lA0 = (char*)As + wid * 1024;
    char* lA1 = (char*)As + 4096 + wid * 1024;
    char* lB0 = (char*)Bs + wid * 1024;
    char* lB1 = (char*)Bs + 4096 + wid * 1024;

    // fragment LDS byte offsets (XOR-swizzled chunk)
    int offA[4], offB[4];
    #pragma unroll
    for (int i = 0; i < 4; ++i) {
        int ra = wm + i * 16 + lo;
        offA[i] = ra * 64 + ((quad ^ ((ra >> 1) & 3)) * 16);
        int rb = wn + i * 16 + lo;
        offB[i] = rb * 64 + ((quad ^ ((rb >> 1) & 3)) * 16);
    }

    f32x4 acc[4][4] = {};
    for (int kt = 0; kt < K / 32; ++kt) {
        if (kt) __syncthreads();
        int ko = kt * 32;
        gload_lds16(gA0 + ko, lA0);
        gload_lds16(gA1 + ko, lA1);
        gload_lds16(gB0 + ko, lB0);
        gload_lds16(gB1 + ko, lB1);
        __syncthreads();
        short8 a[4], b[4];
        #pragma unroll
        for (int i = 0; i < 4; ++i) {
            a[i] = *(const short8*)((const char*)As + offA[i]);
            b[i] = *(const short8*)((const char*)Bs + offB[i]);
        }
        #pragma unroll
        for (int mi = 0; mi < 4; ++mi)
            #pragma unroll
            for (int ni = 0; ni < 4; ++ni)
                acc[mi][ni] = __builtin_amdgcn_mfma_f32_16x16x32_bf16(a[mi], b[ni], acc[mi][ni], 0, 0, 0);
    }
    // epilogue: D layout col=lane&15, row=quad*4+reg
    #pragma unroll
    for (int mi = 0; mi < 4; ++mi)
      #pragma unroll
      for (int ni = 0; ni < 4; ++ni)
        #pragma unroll
        for (int r = 0; r < 4; ++r) {
            int row = mbase + wm + mi * 16 + quad * 4 + r;
            int col = nbase + wn + ni * 16 + lo;
            if (row < M) {
                float v = acc[mi][ni][r] + bias[col];
                if constexpr (RELU_BF16_OUT) {
                    v = fmaxf(v, 0.0f);
                    ((unsigned short*)Cout)[(size_t)row * NOUT + col] = f2bf(v);
                } else {
                    ((float*)Cout)[(size_t)row * NOUT + col] = v;
                }
            }
        }
}

// ---------------- BatchNorm ----------------

__global__ void col_stats1(const float* __restrict__ h, float* __restrict__ partial) {
    int t = threadIdx.x;
    int b = blockIdx.x;
    int r0 = b * 200;
    int r1 = r0 + 200; if (r1 > N_NODES) r1 = N_NODES;
    float s = 0.f, q = 0.f;
    for (int r = r0; r < r1; ++r) {
        float v = h[(size_t)r * DIM + t];
        s += v; q += v * v;
    }
    partial[b * 512 + t] = s;
    partial[b * 512 + 256 + t] = q;
}

__global__ void col_stats2(const float* __restrict__ partial, const float* __restrict__ gamma,
                           const float* __restrict__ beta, float* __restrict__ sc) {
    int t = threadIdx.x;
    float s = 0.f, q = 0.f;
    for (int b = 0; b < 500; ++b) {
        s += partial[b * 512 + t];
        q += partial[b * 512 + 256 + t];
    }
    float mean = s * (1.0f / (float)N_NODES);
    float var = q * (1.0f / (float)N_NODES) - mean * mean;
    float inv = rsqrtf(var + 1e-5f);
    float scale = gamma[t] * inv;
    sc[t] = scale;
    sc[256 + t] = beta[t] - mean * scale;
}

__global__ void bn_apply(const float* __restrict__ h, const float* __restrict__ sc,
                         float* __restrict__ out) {
    long i = (long)blockIdx.x * blockDim.x + threadIdx.x;
    int c = (int)((i * 4) & (DIM - 1));
    float4 v = ((const float4*)h)[i];
    float4 scale = *(const float4*)(sc + c);
    float4 shift = *(const float4*)(sc + 256 + c);
    float4 o;
    o.x = v.x * scale.x + shift.x;
    o.y = v.y * scale.y + shift.y;
    o.z = v.z * scale.z + shift.z;
    o.w = v.w * scale.w + shift.w;
    ((float4*)out)[i] = o;
}

extern "C" void kernel_launch(void* const* d_in, const int* in_sizes, int n_in,
                              void* d_out, int out_size, void* d_ws, size_t ws_size,
                              hipStream_t stream) {
    const float* x     = (const float*)d_in[0];
    const int*   src   = (const int*)d_in[1];
    const int*   dst   = (const int*)d_in[2];
    const float* eps   = (const float*)d_in[3];
    const float* W1    = (const float*)d_in[4];
    const float* b1    = (const float*)d_in[5];
    const float* W2    = (const float*)d_in[6];
    const float* b2    = (const float*)d_in[7];
    const float* gamma = (const float*)d_in[8];
    const float* beta  = (const float*)d_in[9];

    char* ws = (char*)d_ws;
    unsigned short* xb   = (unsigned short*)ws;                   // 51,200,000 B (dead after gather)
    unsigned short* accb = (unsigned short*)(ws + 51200000);      // 51,200,000 B (dead after GEMM1)
    float*          h2   = (float*)ws;                            // 102,400,000 B (overlaps xb+accb, written by GEMM2)
    unsigned short* W1t  = (unsigned short*)(ws + 102400000);     // 262,144 B
    unsigned short* W2t  = (unsigned short*)(ws + 102662144);     // 262,144 B
    float*          sc   = (float*)(ws + 102924288);              // 2,048 B

    // d_out phases: [sort scratch] -> [tbuf bf16 N x 512] -> [partial] -> [final out]
    char* ob = (char*)d_out;
    int* count      = (int*)ob;                    // 400,384 B
    int* start      = (int*)(ob + 400384);         // 400,384 B
    int* cursor     = (int*)(ob + 800768);         // 400,384 B
    int* chunkSums  = (int*)(ob + 1201152);        // 2,048 B
    int* chunkOff   = (int*)(ob + 1203200);        // 2,048 B
    int* sorted_src = (int*)(ob + 1205248);        // 6,400,000 B
    unsigned short* tbuf    = (unsigned short*)d_out;
    float*          partial = (float*)d_out;       // 1,024,000 B, after GEMM2
    float*          out     = (float*)d_out;

    hipLaunchKernelGGL(x2bf, dim3(12500), dim3(256), 0, stream, x, xb);
    hipLaunchKernelGGL(prep_weights, dim3(1024), dim3(256), 0, stream, W1, W2, W1t, W2t);
    hipLaunchKernelGGL(zero_counts, dim3(NCHUNK), dim3(256), 0, stream, count);
    hipLaunchKernelGGL(histogram, dim3(N_EDGES / 256), dim3(256), 0, stream, dst, count);
    hipLaunchKernelGGL(chunk_sums, dim3(NCHUNK), dim3(256), 0, stream, count, chunkSums);
    hipLaunchKernelGGL(scan_chunks, dim3(1), dim3(512), 0, stream, chunkSums, chunkOff);
    hipLaunchKernelGGL(scan_within, dim3(NCHUNK), dim3(256), 0, stream, count, chunkOff, start, cursor);
    hipLaunchKernelGGL(scatter_pos, dim3(N_EDGES / 256), dim3(256), 0, stream, src, dst, cursor, sorted_src);
    hipLaunchKernelGGL(gather_sum, dim3(25000), dim3(256), 0, stream,
                       xb, sorted_src, start, count, eps, accb);
    hipLaunchKernelGGL((gemm128<256, 512, true>), dim3(782 * 4), dim3(256), 0, stream,
                       accb, W1t, b1, (void*)tbuf, N_NODES);
    hipLaunchKernelGGL((gemm128<512, 256, false>), dim3(782 * 2), dim3(256), 0, stream,
                       tbuf, W2t, b2, (void*)h2, N_NODES);
    hipLaunchKernelGGL(col_stats1, dim3(500), dim3(256), 0, stream, h2, partial);
    hipLaunchKernelGGL(col_stats2, dim3(1), dim3(256), 0, stream, partial, gamma, beta, sc);
    hipLaunchKernelGGL(bn_apply, dim3(25000), dim3(256), 0, stream, h2, sc, out);
}